// Round 13
// baseline (250.701 us; speedup 1.0000x reference)
//
#include <hip/hip_runtime.h>
#include <hip/hip_bf16.h>

#define B_ 4
#define LQ_ 2048
#define LK_ 2048
#define E_ 768
#define H_ 12
#define D_ 64
#define SCALE_ 0.03125f
// SCALE * log2(e) folded into Q projection so attention uses bare exp2
#define QSCALE_ 0.04508422f

using short8 = __attribute__((ext_vector_type(8))) short;
using f32x4  = __attribute__((ext_vector_type(4))) float;
using f32x16 = __attribute__((ext_vector_type(16))) float;

template<int N> struct IC { static constexpr int v = N; };

__device__ inline unsigned short f2bf(float f) {
    union { float f; unsigned u; } v; v.f = f;
    unsigned r = (v.u + 0x7FFFu + ((v.u >> 16) & 1u)) >> 16;
    return (unsigned short)r;
}

// pack two fp32 -> two bf16 in one u32 (round-half-up)
__device__ inline unsigned pkbf(float a, float b) {
    union { float f; unsigned u; } x, y; x.f = a; y.f = b;
    return ((x.u + 0x8000u) >> 16) | ((y.u + 0x8000u) & 0xffff0000u);
}

// packed HW convert (v_cvt_pk_bf16_f32 on gfx950)
__device__ inline unsigned pkcvt(float a, float b) {
    float2 p; p.x = a; p.y = b;
    __hip_bfloat162 pb = __float22bfloat162_rn(p);
    union { __hip_bfloat162 h; unsigned u; } c; c.h = pb;
    return c.u;
}

// async global->LDS, 16B per lane; LDS dest = uniform base + lane*16
__device__ inline void gll16(const void* g, void* l) {
    __builtin_amdgcn_global_load_lds(
        (const __attribute__((address_space(1))) unsigned int*)g,
        (__attribute__((address_space(3))) unsigned int*)l, 16, 0, 0);
}

// ---------------- merged LayerNorm (both inputs) + weight transpose/cast ----------
// bid < 4096: LN wave-per-row (4 rows/block over xq then xkv)
// bid >= 4096: 3456 transpose blocks (48 x 24 x 3 decoded from linear id)
__global__ __launch_bounds__(256) void ln_tr_kernel(
    const float* __restrict__ xq, const float* __restrict__ xkv,
    const float* __restrict__ gq, const float* __restrict__ bq,
    const float* __restrict__ gk, const float* __restrict__ bk,
    unsigned short* __restrict__ yq, unsigned short* __restrict__ ykv,
    const float* __restrict__ Wq, const float* __restrict__ Wkv, const float* __restrict__ Wo,
    unsigned short* __restrict__ WqT, unsigned short* __restrict__ WkvT, unsigned short* __restrict__ WoT)
{
    __shared__ float tile[32][33];
    int bid = blockIdx.x;
    if (bid < 4096) {
        int wave = threadIdx.x >> 6, lane = threadIdx.x & 63;
        int row = bid * 4 + wave;          // 0..16383
        const float* x; const float* g; const float* be; unsigned short* y;
        if (row < 8192) { x = xq; g = gq; be = bq; y = yq; }
        else { row -= 8192; x = xkv; g = gk; be = bk; y = ykv; }
        const float* xr = x + (size_t)row * E_;
        float4 v[3];
        float s = 0.f;
#pragma unroll
        for (int i = 0; i < 3; i++) {
            v[i] = *(const float4*)(xr + i * 256 + lane * 4);
            s += v[i].x + v[i].y + v[i].z + v[i].w;
        }
#pragma unroll
        for (int off = 32; off >= 1; off >>= 1) s += __shfl_xor(s, off);
        float mu = s * (1.0f / E_);
        float q = 0.f;
#pragma unroll
        for (int i = 0; i < 3; i++) {
            float dx = v[i].x - mu, dy = v[i].y - mu, dz = v[i].z - mu, dw = v[i].w - mu;
            q += dx * dx + dy * dy + dz * dz + dw * dw;
        }
#pragma unroll
        for (int off = 32; off >= 1; off >>= 1) q += __shfl_xor(q, off);
        float rstd = rsqrtf(q * (1.0f / E_) + 1e-5f);
        unsigned short* yr = y + (size_t)row * E_;
#pragma unroll
        for (int i = 0; i < 3; i++) {
            int c = i * 256 + lane * 4;
            float4 gv = *(const float4*)(g + c);
            float4 bv = *(const float4*)(be + c);
            ushort4 o;
            o.x = f2bf((v[i].x - mu) * rstd * gv.x + bv.x);
            o.y = f2bf((v[i].y - mu) * rstd * gv.y + bv.y);
            o.z = f2bf((v[i].z - mu) * rstd * gv.z + bv.z);
            o.w = f2bf((v[i].w - mu) * rstd * gv.w + bv.w);
            *(ushort4*)(yr + c) = o;
        }
        return;
    }
    // transpose part
    int b2 = bid - 4096;            // 0..3455
    int z = b2 / 1152;              // 0..2
    int rem = b2 - z * 1152;        // 48 x 24
    int bx = rem % 48, by = rem / 48;
    const float* in; unsigned short* out; int C;
    if (z == 0)      { in = Wq;  out = WqT;  C = E_; }
    else if (z == 1) { in = Wkv; out = WkvT; C = 2 * E_; }
    else             { in = Wo;  out = WoT;  C = E_; }
    int c0 = bx * 32, r0 = by * 32;
    if (c0 >= C) return;
    int tx = threadIdx.x & 31, ty = threadIdx.x >> 5;
#pragma unroll
    for (int i = 0; i < 32; i += 8)
        tile[ty + i][tx] = in[(size_t)(r0 + ty + i) * C + c0 + tx];
    __syncthreads();
#pragma unroll
    for (int i = 0; i < 32; i += 8)
        out[(size_t)(c0 + ty + i) * E_ + r0 + tx] = f2bf(tile[tx][ty + i]);
}

// ---------------- GEMM body: C[M][N] = A[M][K] * Bt[N][K]^T, bf16, gll + swizzle ---
// mode 0: RoPE + QSCALE -> Q[B,H,L,64];  mode 1: K w/ RoPE, V transposed -> Vt;
// mode 2: gain*(v+bo) fp32.
#define BN 128
#define BK 64
template<int BMT>
__device__ __forceinline__ void gemm_body(
    const unsigned short* __restrict__ A, const unsigned short* __restrict__ Bt,
    int K, int mode, int bm, int bn,
    unsigned short* __restrict__ outQ, const float* __restrict__ freqs,
    unsigned short* __restrict__ outK, unsigned short* __restrict__ outV,
    float* __restrict__ outF, const float* __restrict__ bo, const float* __restrict__ gain)
{
    constexpr int MT = (BMT == 128) ? 4 : 2;             // 16-row m-tiles per wave
    constexpr int SMEMN = (BMT == 128) ? 128 * 136 : (BMT * 64 + 128 * 64);
    __shared__ __align__(16) unsigned short smem[SMEMN];
    auto Asm = (unsigned short (*)[BK])smem;             // [BMT][64]
    auto Bsm = (unsigned short (*)[BK])(smem + BMT * BK);// [128][64]

    int tid = threadIdx.x;
    int wave = tid >> 6, lane = tid & 63;
    int quad = lane >> 4, l16 = lane & 15;
    int waveM = (wave >> 1) * (MT * 16), waveN = (wave & 1) * 64;
    int ro = lane >> 3, cx = lane & 7;
    int sco = ((cx ^ ro) * 8);           // swizzled global chunk offset (elements)

    f32x4 acc[MT][4] = {};

    for (int k0 = 0; k0 < K; k0 += BK) {
        const unsigned short* Ag = A + (size_t)(bm + wave * (BMT / 4) + ro) * K + k0 + sco;
        const unsigned short* Bg = Bt + (size_t)(bn + wave * 32 + ro) * K + k0 + sco;
#pragma unroll
        for (int i = 0; i < BMT / 32; i++)
            gll16(Ag + (size_t)(i * 8) * K, &Asm[wave * (BMT / 4) + i * 8][0]);
#pragma unroll
        for (int i = 0; i < 4; i++)
            gll16(Bg + (size_t)(i * 8) * K, &Bsm[wave * 32 + i * 8][0]);
        __syncthreads();
#pragma unroll
        for (int kk = 0; kk < BK; kk += 32) {
            short8 fa[MT], fb[4];
#pragma unroll
            for (int t = 0; t < 4; t++) {
                int pos = ((quad + (kk >> 3)) ^ (l16 & 7)) * 8;
                if (t < MT) fa[t] = *(const short8*)(&Asm[waveM + t * 16 + l16][pos]);
                fb[t] = *(const short8*)(&Bsm[waveN + t * 16 + l16][pos]);
            }
#pragma unroll
            for (int mt = 0; mt < MT; mt++)
#pragma unroll
                for (int nt = 0; nt < 4; nt++)
                    acc[mt][nt] = __builtin_amdgcn_mfma_f32_16x16x32_bf16(fa[mt], fb[nt], acc[mt][nt], 0, 0, 0);
        }
        __syncthreads();
    }

    if (BMT == 128 && mode == 1 && bn >= E_) {
        // ---- V block: transposed store via LDS bounce -> Vt[bh][d][key] ----
        auto T = (unsigned short (*)[136])smem;
#pragma unroll
        for (int mt = 0; mt < MT; mt++) {
#pragma unroll
            for (int nt = 0; nt < 4; nt++) {
                int ml = waveM + mt * 16 + quad * 4;
                int nl = waveN + nt * 16 + l16;
                *(unsigned*)&T[nl][ml]     = pkbf(acc[mt][nt][0], acc[mt][nt][1]);
                *(unsigned*)&T[nl][ml + 2] = pkbf(acc[mt][nt][2], acc[mt][nt][3]);
            }
        }
        __syncthreads();
        int nnbase = bn - E_;
        int bb = bm >> 11, l0 = bm & (LQ_ - 1);
#pragma unroll
        for (int it = 0; it < 8; it++) {
            int row = it * 16 + (tid >> 4);
            int hh = (nnbase + row) >> 6, dd = (nnbase + row) & 63;
            short8 v = *(const short8*)&T[row][(tid & 15) * 8];
            *(short8*)(outV + (((size_t)bb * H_ + hh) * D_ + dd) * LK_ + l0 + (tid & 15) * 8) = v;
        }
        return;
    }

    float gg = (mode == 2) ? gain[0] : 0.f;
#pragma unroll
    for (int mt = 0; mt < MT; mt++) {
#pragma unroll
        for (int nt = 0; nt < 4; nt++) {
#pragma unroll
            for (int r = 0; r < 4; r++) {
                int m = bm + waveM + mt * 16 + quad * 4 + r;
                int n = bn + waveN + nt * 16 + l16;
                float v = acc[mt][nt][r];
                if (mode == 2) {
                    outF[(size_t)m * E_ + n] = gg * (v + bo[n]);
                } else {
                    int l = m & (LQ_ - 1), bb = m >> 11;
                    float partner = __shfl_xor(v, 1);
                    int h = n >> 6, dd = n & 63;
                    const float* f = freqs + ((size_t)l * 32 + (dd >> 1)) * 2;
                    float f0 = f[0], f1 = f[1];
                    float o = ((dd & 1) == 0) ? (v * f0 - partner * f1)
                                              : (partner * f1 + v * f0);
                    if (mode == 0) o *= QSCALE_;
                    unsigned short* dst = (mode == 0) ? outQ : outK;
                    dst[(((size_t)bb * H_ + h) * LQ_ + l) * D_ + dd] = f2bf(o);
                }
            }
        }
    }
}

template<int BMT>
__global__ __launch_bounds__(256) void gemm_kernel(
    const unsigned short* __restrict__ A, const unsigned short* __restrict__ Bt,
    int K, int mode,
    unsigned short* __restrict__ outQ, const float* __restrict__ freqs,
    unsigned short* __restrict__ outK, unsigned short* __restrict__ outV,
    float* __restrict__ outF, const float* __restrict__ bo, const float* __restrict__ gain)
{
    gemm_body<BMT>(A, Bt, K, mode, blockIdx.x * BMT, blockIdx.y * BN,
                   outQ, freqs, outK, outV, outF, bo, gain);
}

// ---------------- merged Q-proj + KV-proj, both at BMT=128, one launch ------------
// bid < 768:  KV proj (64 m-tiles x 12 n-tiles), mode 1
// bid >= 768: Q  proj (64 m-tiles x  6 n-tiles), mode 0
// Single gemm_body call site so only one 34.8 KB LDS allocation.
// NOTE: default round-robin bid->XCD mapping partitions A-panels across XCDs
// (x = bid mod 64; XCD k gets x === k mod 8 -> 1.57 MB A working set per XCD,
// L2-resident, reused 12x). A contiguous-chunk XCD swizzle would give each XCD
// the whole 12.6 MB A -- analytically worse; do not swizzle this grid.
__global__ __launch_bounds__(256) void proj_kernel(
    const unsigned short* __restrict__ xq_ln, const unsigned short* __restrict__ xkv_ln,
    const unsigned short* __restrict__ WqT, const unsigned short* __restrict__ WkvT,
    unsigned short* __restrict__ Qb, unsigned short* __restrict__ Kb,
    unsigned short* __restrict__ Vt,
    const float* __restrict__ freqs_q, const float* __restrict__ freqs_k)
{
    int bid = blockIdx.x;
    const unsigned short* A; const unsigned short* Bt; int mode, bm, bn;
    const float* fr; unsigned short* oQ; unsigned short* oK; unsigned short* oV;
    if (bid < 768) {
        int x = bid & 63, y = bid >> 6;       // 64 x 12
        A = xkv_ln; Bt = WkvT; mode = 1; bm = x * 128; bn = y * 128;
        fr = freqs_k; oQ = nullptr; oK = Kb; oV = Vt;
    } else {
        int b2 = bid - 768;
        int x = b2 & 63, y = b2 >> 6;         // 64 x 6
        A = xq_ln; Bt = WqT; mode = 0; bm = x * 128; bn = y * 128;
        fr = freqs_q; oQ = Qb; oK = nullptr; oV = nullptr;
    }
    gemm_body<128>(A, Bt, E_, mode, bm, bn, oQ, fr, oK, oV, nullptr, nullptr, nullptr);
}

// ---------------- flash attention: 32x32 MFMA, register P-transform, 3-buf gll -----
// grid: (x = bh  [XCD-stationary K/V], y = q-block)
// Round-13: r12 (verified best: attn 79 us, total 249.1) + ONE change:
// block phase-stagger. Accounting shows ~48% of SIMD issue slots idle
// (5920 cyc/tile-round vs ~3040 demanded by 3 resident waves). Theory:
// the 3 co-resident blocks per CU (linear ids {c, c+256, c+512} under
// round-robin dispatch) start together and run identical-duration barriered
// tile loops -> phase-locked; all 12 waves burst QK (matrix pipe) then all
// burst softmax (VALU) with no cross-phase overlap. Fix: one-time s_sleep
// stagger of 0/1024/2048 cyc by (linear_bid >> 8) -- ~1/3 and ~2/3 of the
// ~2 kcyc tile period -- so co-resident blocks interleave phases.
// Pure delay: numerics bit-identical to r12.
// CORRECTNESS NOTE (r11): the s_setprio brackets are LOAD-BEARING spacers
// around the permlane->MFMA sequence -- do not remove without re-verifying.
// VGPR law (r7/r8/r10): <=84 VGPR keeps ~25% occupancy; >=96 drops to ~17%.
__global__ __launch_bounds__(256, 4) void attn_kernel(
    const unsigned short* __restrict__ Qg, const unsigned short* __restrict__ Kg,
    const unsigned short* __restrict__ Vt, unsigned short* __restrict__ O)
{
    // [0..12287] K bufs (3 x 4096 shorts), [12288..24575] V bufs
    __shared__ __align__(16) unsigned short smem[3 * 4096 * 2];

    int tid = threadIdx.x;
    int wave = tid >> 6, lane = tid & 63;
    int l32 = lane & 31, hi = lane >> 5;
    int bh = blockIdx.x;
    int b = bh / H_, h = bh % H_;
    int qbase = blockIdx.y * 128 + wave * 32;

    // de-phase co-resident blocks: {c, c+256, c+512} share a CU under
    // round-robin dispatch -> stagger classes 0/1/2.
    int grp = (blockIdx.x + 48 * blockIdx.y) >> 8;   // 0,1,2
    if (grp == 1)      __builtin_amdgcn_s_sleep(16); // ~1024 cyc
    else if (grp == 2) __builtin_amdgcn_s_sleep(32); // ~2048 cyc

    const size_t head = (size_t)bh * LK_ * D_;
    const unsigned short* Qh = Qg + head;
    const unsigned short* Kh = Kg + head;
    const unsigned short* Vh = Vt + head;   // [d][key]

    // Q fragments: B-operand [k=d][n=q]: lane(n=l32,hi): d = dc*16 + hi*8 + j
    short8 qf[4];
#pragma unroll
    for (int dc = 0; dc < 4; dc++)
        qf[dc] = *(const short8*)(Qh + (size_t)(qbase + l32) * D_ + dc * 16 + hi * 8);

    f32x16 oacc[2] = {};
    float lsum = 0.f;

    int ro = lane >> 3, cx = lane & 7;
    int sco = ((cx ^ ro) * 8);
    int sw = l32 & 7;
    int hs = hi ^ sw;

    // 4 per-lane LDS element-offset bases; all 16 per-tile ds_reads are
    // bs[c] + compile-time offset. (c = dc for QK, c = half*2+kk for PV.)
    // Identity: ((c*2+hi)^sw)*8 == ((c*2)^(hi^sw))*8  (c*2 even, hi bit0).
    unsigned bs[4];
#pragma unroll
    for (int c = 0; c < 4; c++)
        bs[c] = l32 * 64 + (((c * 2) ^ hs) * 8);

    // staging base pointers (tile 0), advanced by constants per stage
    const unsigned short* kst = Kh + (size_t)(wave * 16 + ro) * D_ + sco;
    const unsigned short* vst = Vh + (size_t)(wave * 16 + ro) * LK_ + sco;

    // stage tile (ptrs pre-offset) into LDS buffer bf
    auto stage = [&](const unsigned short* Kp, const unsigned short* Vp, int bf) {
        gll16(Kp,            &smem[bf * 4096 + (wave * 16) * 64]);
        gll16(Kp + 8 * D_,   &smem[bf * 4096 + (wave * 16 + 8) * 64]);
        gll16(Vp,            &smem[12288 + bf * 4096 + (wave * 16) * 64]);
        gll16(Vp + 8 * LK_,  &smem[12288 + bf * 4096 + (wave * 16 + 8) * 64]);
    };

    // compute one 64-key tile from buffer BF (compile-time)
    auto compute = [&](auto bfc) {
        constexpr int bf = decltype(bfc)::v;
        constexpr int KO = bf * 4096;            // K buf base (shorts)
        constexpr int VO = 12288 + bf * 4096;    // V buf base (shorts)

        // Both halves' S^T chains, interleaved (independent MFMA chains).
        f32x16 st0 = {}, st1 = {};
        __builtin_amdgcn_s_setprio(1);
#pragma unroll
        for (int dc = 0; dc < 4; dc++) {
            short8 k0 = *(const short8*)&smem[bs[dc] + KO];
            short8 k1 = *(const short8*)&smem[bs[dc] + KO + 2048];
            st0 = __builtin_amdgcn_mfma_f32_32x32x16_bf16(k0, qf[dc], st0, 0, 0, 0);
            st1 = __builtin_amdgcn_mfma_f32_32x32x16_bf16(k1, qf[dc], st1, 0, 0, 0);
        }
        __builtin_amdgcn_s_setprio(0);

        // softmax batch: exp2 + lsum (VALU) + packed bf16 convert, both halves
        unsigned pks0[8], pks1[8];
#pragma unroll
        for (int t = 0; t < 8; t++) {
            float p0 = __builtin_amdgcn_exp2f(st0[2 * t]);
            float p1 = __builtin_amdgcn_exp2f(st0[2 * t + 1]);
            lsum += p0 + p1;
            pks0[t] = pkcvt(p0, p1);
        }
#pragma unroll
        for (int t = 0; t < 8; t++) {
            float p0 = __builtin_amdgcn_exp2f(st1[2 * t]);
            float p1 = __builtin_amdgcn_exp2f(st1[2 * t + 1]);
            lsum += p0 + p1;
            pks1[t] = pkcvt(p0, p1);
        }
        // cross-half key exchange, in-register: after the swaps,
        // pks[kk*4 .. kk*4+3] are exactly the PV A-fragment words g0..g3.
        asm("v_permlane32_swap_b32 %0, %1" : "+v"(pks0[0]), "+v"(pks0[2]));
        asm("v_permlane32_swap_b32 %0, %1" : "+v"(pks0[1]), "+v"(pks0[3]));
        asm("v_permlane32_swap_b32 %0, %1" : "+v"(pks0[4]), "+v"(pks0[6]));
        asm("v_permlane32_swap_b32 %0, %1" : "+v"(pks0[5]), "+v"(pks0[7]));
        asm("v_permlane32_swap_b32 %0, %1" : "+v"(pks1[0]), "+v"(pks1[2]));
        asm("v_permlane32_swap_b32 %0, %1" : "+v"(pks1[1]), "+v"(pks1[3]));
        asm("v_permlane32_swap_b32 %0, %1" : "+v"(pks1[4]), "+v"(pks1[6]));
        asm("v_permlane32_swap_b32 %0, %1" : "+v"(pks1[5]), "+v"(pks1[7]));

        // PV: A = P[q][key] assembled in-register, B = Vt[d][key].
        __builtin_amdgcn_s_setprio(1);
#pragma unroll
        for (int half = 0; half < 2; half++) {
#pragma unroll
            for (int kk = 0; kk < 2; kk++) {
                union { unsigned u[4]; short8 s8; } pf;
#pragma unroll
                for (int g = 0; g < 4; g++)
                    pf.u[g] = half ? pks1[kk * 4 + g] : pks0[kk * 4 + g];
#pragma unroll
                for (int dt = 0; dt < 2; dt++) {
                    short8 vfr = *(const short8*)&smem[bs[half * 2 + kk] + VO + dt * 2048];
                    oacc[dt] = __builtin_amdgcn_mfma_f32_32x32x16_bf16(pf.s8, vfr, oacc[dt], 0, 0, 0);
                }
            }
        }
        __builtin_amdgcn_s_setprio(0);
    };

    // prologue: stage tiles 0 and 1
    stage(kst, vst, 0);
    stage(kst + 4096, vst + 64, 1);
    asm volatile("s_waitcnt vmcnt(4)\ns_barrier" ::: "memory");

    // main loop: tiles 0..29, unrolled x3 so buf index is compile-time;
    // depth-2 prefetch, one barrier per tile.
    for (int it = 0; it < 10; ++it) {
        int t = 3 * it;
        stage(kst + (size_t)(t + 2) * 4096, vst + (size_t)(t + 2) * 64, 2);
        compute(IC<0>{});
        asm volatile("s_waitcnt vmcnt(4) lgkmcnt(0)\ns_barrier" ::: "memory");
        stage(kst + (size_t)(t + 3) * 4096, vst + (size_t)(t + 3) * 64, 0);
        compute(IC<1>{});
        asm volatile("s_waitcnt vmcnt(4) lgkmcnt(0)\ns_barrier" ::: "memory");
        stage(kst + (size_t)(t + 4) * 4096, vst + (size_t)(t + 4) * 64, 1);
        compute(IC<2>{});
        asm volatile("s_waitcnt vmcnt(4) lgkmcnt(0)\ns_barrier" ::: "memory");
    }
    // tile 30 (buf 0): nothing new to stage; drain tile 31's loads
    compute(IC<0>{});
    asm volatile("s_waitcnt vmcnt(0) lgkmcnt(0)\ns_barrier" ::: "memory");
    // tile 31 (buf 1)
    compute(IC<1>{});

    // epilogue: total row sums, normalize, store
    lsum += __shfl_xor(lsum, 32);
    float inv = 1.f / lsum;
#pragma unroll
    for (int reg = 0; reg < 16; reg++) {
        int ql = (reg & 3) + 8 * (reg >> 2) + 4 * hi;
        float iq = __shfl(inv, ql);
        int q = qbase + ql;
        size_t base = ((size_t)b * LQ_ + q) * E_ + h * D_;
#pragma unroll
        for (int dt = 0; dt < 2; dt++)
            O[base + dt * 32 + l32] = f2bf(oacc[dt][reg] * iq);
    }
}

extern "C" void kernel_launch(void* const* d_in, const int* in_sizes, int n_in,
                              void* d_out, int out_size, void* d_ws, size_t ws_size,
                              hipStream_t stream)
{
    const float* x_q     = (const float*)d_in[0];
    const float* x_kv    = (const float*)d_in[1];
    const float* freqs_q = (const float*)d_in[2];
    const float* freqs_k = (const float*)d_in[3];
    const float* Wq      = (const float*)d_in[4];
    const float* Wkv     = (const float*)d_in[5];
    const float* Wo      = (const float*)d_in[6];
    const float* bo      = (const float*)d_in[7];
    const float* ln_q_g  = (const float*)d_in[8];
    const float* ln_q_b  = (const float*)d_in[9];
    const float* ln_kv_g = (const float*)d_in[10];
    const float* ln_kv_b = (const float*)d_in[11];
    const float* gain    = (const float*)d_in[12];
    float* out = (float*)d_out;

    unsigned short* ws = (unsigned short*)d_ws;
    const size_t SZ = (size_t)B_ * LQ_ * E_;  // 6291456
    unsigned short* xq_ln  = ws;
    unsigned short* xkv_ln = xq_ln + SZ;
    unsigned short* Qb     = xkv_ln + SZ;
    unsigned short* Kb     = Qb + SZ;
    unsigned short* Vt     = Kb + SZ;          // filled transposed by KV-GEMM
    unsigned short* Ob     = xq_ln;            // reuse (dead after Q GEMM)
    unsigned short* WqT    = Vt + SZ;
    unsigned short* WkvT   = WqT + E_ * E_;
    unsigned short* WoT    = WkvT + 2 * E_ * E_;

    ln_tr_kernel<<<7552, 256, 0, stream>>>(x_q, x_kv, ln_q_g, ln_q_b, ln_kv_g, ln_kv_b,
                                           xq_ln, xkv_ln, Wq, Wkv, Wo, WqT, WkvT, WoT);
    proj_kernel<<<1152, 256, 0, stream>>>(xq_ln, xkv_ln, WqT, WkvT, Qb, Kb, Vt,
                                          freqs_q, freqs_k);
    attn_kernel<<<dim3(48, 16), 256, 0, stream>>>(Qb, Kb, Vt, Ob);
    // O-proj at BMT=64: grid (128,6) = 768 blocks = exactly 3.0 blocks/CU.
    // (r9: BMT=128's 384 blocks = 1.5/CU load imbalance cost +35 us -- tile
    // efficiency is subordinate to grid/CU balance at small grids.)
    gemm_kernel<64><<<dim3(128, 6), 256, 0, stream>>>(Ob, WoT, E_, 2,
                                                      nullptr, nullptr, nullptr, nullptr, out, bo, gain);
}

// Round 14
// 244.744 us; speedup vs baseline: 1.0243x; 1.0243x over previous
//
#include <hip/hip_runtime.h>
#include <hip/hip_bf16.h>

#define B_ 4
#define LQ_ 2048
#define LK_ 2048
#define E_ 768
#define H_ 12
#define D_ 64
#define SCALE_ 0.03125f
// SCALE * log2(e) folded into Q projection so attention uses bare exp2
#define QSCALE_ 0.04508422f

using short8 = __attribute__((ext_vector_type(8))) short;
using f32x4  = __attribute__((ext_vector_type(4))) float;
using f32x16 = __attribute__((ext_vector_type(16))) float;

template<int N> struct IC { static constexpr int v = N; };

__device__ inline unsigned short f2bf(float f) {
    union { float f; unsigned u; } v; v.f = f;
    unsigned r = (v.u + 0x7FFFu + ((v.u >> 16) & 1u)) >> 16;
    return (unsigned short)r;
}

// pack two fp32 -> two bf16 in one u32 (round-half-up)
__device__ inline unsigned pkbf(float a, float b) {
    union { float f; unsigned u; } x, y; x.f = a; y.f = b;
    return ((x.u + 0x8000u) >> 16) | ((y.u + 0x8000u) & 0xffff0000u);
}

// packed HW convert (v_cvt_pk_bf16_f32 on gfx950)
__device__ inline unsigned pkcvt(float a, float b) {
    float2 p; p.x = a; p.y = b;
    __hip_bfloat162 pb = __float22bfloat162_rn(p);
    union { __hip_bfloat162 h; unsigned u; } c; c.h = pb;
    return c.u;
}

// async global->LDS, 16B per lane; LDS dest = uniform base + lane*16
__device__ inline void gll16(const void* g, void* l) {
    __builtin_amdgcn_global_load_lds(
        (const __attribute__((address_space(1))) unsigned int*)g,
        (__attribute__((address_space(3))) unsigned int*)l, 16, 0, 0);
}

// ---------------- merged LayerNorm (both inputs) + weight transpose/cast ----------
// bid < 4096: LN wave-per-row (4 rows/block over xq then xkv)
// bid >= 4096: 3456 transpose blocks (48 x 24 x 3 decoded from linear id)
__global__ __launch_bounds__(256) void ln_tr_kernel(
    const float* __restrict__ xq, const float* __restrict__ xkv,
    const float* __restrict__ gq, const float* __restrict__ bq,
    const float* __restrict__ gk, const float* __restrict__ bk,
    unsigned short* __restrict__ yq, unsigned short* __restrict__ ykv,
    const float* __restrict__ Wq, const float* __restrict__ Wkv, const float* __restrict__ Wo,
    unsigned short* __restrict__ WqT, unsigned short* __restrict__ WkvT, unsigned short* __restrict__ WoT)
{
    __shared__ float tile[32][33];
    int bid = blockIdx.x;
    if (bid < 4096) {
        int wave = threadIdx.x >> 6, lane = threadIdx.x & 63;
        int row = bid * 4 + wave;          // 0..16383
        const float* x; const float* g; const float* be; unsigned short* y;
        if (row < 8192) { x = xq; g = gq; be = bq; y = yq; }
        else { row -= 8192; x = xkv; g = gk; be = bk; y = ykv; }
        const float* xr = x + (size_t)row * E_;
        float4 v[3];
        float s = 0.f;
#pragma unroll
        for (int i = 0; i < 3; i++) {
            v[i] = *(const float4*)(xr + i * 256 + lane * 4);
            s += v[i].x + v[i].y + v[i].z + v[i].w;
        }
#pragma unroll
        for (int off = 32; off >= 1; off >>= 1) s += __shfl_xor(s, off);
        float mu = s * (1.0f / E_);
        float q = 0.f;
#pragma unroll
        for (int i = 0; i < 3; i++) {
            float dx = v[i].x - mu, dy = v[i].y - mu, dz = v[i].z - mu, dw = v[i].w - mu;
            q += dx * dx + dy * dy + dz * dz + dw * dw;
        }
#pragma unroll
        for (int off = 32; off >= 1; off >>= 1) q += __shfl_xor(q, off);
        float rstd = rsqrtf(q * (1.0f / E_) + 1e-5f);
        unsigned short* yr = y + (size_t)row * E_;
#pragma unroll
        for (int i = 0; i < 3; i++) {
            int c = i * 256 + lane * 4;
            float4 gv = *(const float4*)(g + c);
            float4 bv = *(const float4*)(be + c);
            ushort4 o;
            o.x = f2bf((v[i].x - mu) * rstd * gv.x + bv.x);
            o.y = f2bf((v[i].y - mu) * rstd * gv.y + bv.y);
            o.z = f2bf((v[i].z - mu) * rstd * gv.z + bv.z);
            o.w = f2bf((v[i].w - mu) * rstd * gv.w + bv.w);
            *(ushort4*)(yr + c) = o;
        }
        return;
    }
    // transpose part
    int b2 = bid - 4096;            // 0..3455
    int z = b2 / 1152;              // 0..2
    int rem = b2 - z * 1152;        // 48 x 24
    int bx = rem % 48, by = rem / 48;
    const float* in; unsigned short* out; int C;
    if (z == 0)      { in = Wq;  out = WqT;  C = E_; }
    else if (z == 1) { in = Wkv; out = WkvT; C = 2 * E_; }
    else             { in = Wo;  out = WoT;  C = E_; }
    int c0 = bx * 32, r0 = by * 32;
    if (c0 >= C) return;
    int tx = threadIdx.x & 31, ty = threadIdx.x >> 5;
#pragma unroll
    for (int i = 0; i < 32; i += 8)
        tile[ty + i][tx] = in[(size_t)(r0 + ty + i) * C + c0 + tx];
    __syncthreads();
#pragma unroll
    for (int i = 0; i < 32; i += 8)
        out[(size_t)(c0 + ty + i) * E_ + r0 + tx] = f2bf(tile[tx][ty + i]);
}

// ---------------- GEMM body: C[M][N] = A[M][K] * Bt[N][K]^T, bf16, gll + swizzle ---
// mode 0: RoPE + QSCALE -> Q[B,H,L,64];  mode 1: K w/ RoPE, V transposed -> Vt;
// mode 2: gain*(v+bo) fp32.
#define BN 128
#define BK 64
template<int BMT>
__device__ __forceinline__ void gemm_body(
    const unsigned short* __restrict__ A, const unsigned short* __restrict__ Bt,
    int K, int mode, int bm, int bn,
    unsigned short* __restrict__ outQ, const float* __restrict__ freqs,
    unsigned short* __restrict__ outK, unsigned short* __restrict__ outV,
    float* __restrict__ outF, const float* __restrict__ bo, const float* __restrict__ gain)
{
    constexpr int MT = (BMT == 128) ? 4 : 2;             // 16-row m-tiles per wave
    constexpr int SMEMN = (BMT == 128) ? 128 * 136 : (BMT * 64 + 128 * 64);
    __shared__ __align__(16) unsigned short smem[SMEMN];
    auto Asm = (unsigned short (*)[BK])smem;             // [BMT][64]
    auto Bsm = (unsigned short (*)[BK])(smem + BMT * BK);// [128][64]

    int tid = threadIdx.x;
    int wave = tid >> 6, lane = tid & 63;
    int quad = lane >> 4, l16 = lane & 15;
    int waveM = (wave >> 1) * (MT * 16), waveN = (wave & 1) * 64;
    int ro = lane >> 3, cx = lane & 7;
    int sco = ((cx ^ ro) * 8);           // swizzled global chunk offset (elements)

    f32x4 acc[MT][4] = {};

    for (int k0 = 0; k0 < K; k0 += BK) {
        const unsigned short* Ag = A + (size_t)(bm + wave * (BMT / 4) + ro) * K + k0 + sco;
        const unsigned short* Bg = Bt + (size_t)(bn + wave * 32 + ro) * K + k0 + sco;
#pragma unroll
        for (int i = 0; i < BMT / 32; i++)
            gll16(Ag + (size_t)(i * 8) * K, &Asm[wave * (BMT / 4) + i * 8][0]);
#pragma unroll
        for (int i = 0; i < 4; i++)
            gll16(Bg + (size_t)(i * 8) * K, &Bsm[wave * 32 + i * 8][0]);
        __syncthreads();
#pragma unroll
        for (int kk = 0; kk < BK; kk += 32) {
            short8 fa[MT], fb[4];
#pragma unroll
            for (int t = 0; t < 4; t++) {
                int pos = ((quad + (kk >> 3)) ^ (l16 & 7)) * 8;
                if (t < MT) fa[t] = *(const short8*)(&Asm[waveM + t * 16 + l16][pos]);
                fb[t] = *(const short8*)(&Bsm[waveN + t * 16 + l16][pos]);
            }
#pragma unroll
            for (int mt = 0; mt < MT; mt++)
#pragma unroll
                for (int nt = 0; nt < 4; nt++)
                    acc[mt][nt] = __builtin_amdgcn_mfma_f32_16x16x32_bf16(fa[mt], fb[nt], acc[mt][nt], 0, 0, 0);
        }
        __syncthreads();
    }

    if (BMT == 128 && mode == 1 && bn >= E_) {
        // ---- V block: transposed store via LDS bounce -> Vt[bh][d][key] ----
        auto T = (unsigned short (*)[136])smem;
#pragma unroll
        for (int mt = 0; mt < MT; mt++) {
#pragma unroll
            for (int nt = 0; nt < 4; nt++) {
                int ml = waveM + mt * 16 + quad * 4;
                int nl = waveN + nt * 16 + l16;
                *(unsigned*)&T[nl][ml]     = pkbf(acc[mt][nt][0], acc[mt][nt][1]);
                *(unsigned*)&T[nl][ml + 2] = pkbf(acc[mt][nt][2], acc[mt][nt][3]);
            }
        }
        __syncthreads();
        int nnbase = bn - E_;
        int bb = bm >> 11, l0 = bm & (LQ_ - 1);
#pragma unroll
        for (int it = 0; it < 8; it++) {
            int row = it * 16 + (tid >> 4);
            int hh = (nnbase + row) >> 6, dd = (nnbase + row) & 63;
            short8 v = *(const short8*)&T[row][(tid & 15) * 8];
            *(short8*)(outV + (((size_t)bb * H_ + hh) * D_ + dd) * LK_ + l0 + (tid & 15) * 8) = v;
        }
        return;
    }

    float gg = (mode == 2) ? gain[0] : 0.f;
#pragma unroll
    for (int mt = 0; mt < MT; mt++) {
#pragma unroll
        for (int nt = 0; nt < 4; nt++) {
#pragma unroll
            for (int r = 0; r < 4; r++) {
                int m = bm + waveM + mt * 16 + quad * 4 + r;
                int n = bn + waveN + nt * 16 + l16;
                float v = acc[mt][nt][r];
                if (mode == 2) {
                    outF[(size_t)m * E_ + n] = gg * (v + bo[n]);
                } else {
                    int l = m & (LQ_ - 1), bb = m >> 11;
                    float partner = __shfl_xor(v, 1);
                    int h = n >> 6, dd = n & 63;
                    const float* f = freqs + ((size_t)l * 32 + (dd >> 1)) * 2;
                    float f0 = f[0], f1 = f[1];
                    float o = ((dd & 1) == 0) ? (v * f0 - partner * f1)
                                              : (partner * f1 + v * f0);
                    if (mode == 0) o *= QSCALE_;
                    unsigned short* dst = (mode == 0) ? outQ : outK;
                    dst[(((size_t)bb * H_ + h) * LQ_ + l) * D_ + dd] = f2bf(o);
                }
            }
        }
    }
}

template<int BMT>
__global__ __launch_bounds__(256) void gemm_kernel(
    const unsigned short* __restrict__ A, const unsigned short* __restrict__ Bt,
    int K, int mode,
    unsigned short* __restrict__ outQ, const float* __restrict__ freqs,
    unsigned short* __restrict__ outK, unsigned short* __restrict__ outV,
    float* __restrict__ outF, const float* __restrict__ bo, const float* __restrict__ gain)
{
    gemm_body<BMT>(A, Bt, K, mode, blockIdx.x * BMT, blockIdx.y * BN,
                   outQ, freqs, outK, outV, outF, bo, gain);
}

// ---------------- merged Q-proj + KV-proj, both at BMT=128, one launch ------------
// bid < 768:  KV proj (64 m-tiles x 12 n-tiles), mode 1
// bid >= 768: Q  proj (64 m-tiles x  6 n-tiles), mode 0
// Single gemm_body call site so only one 34.8 KB LDS allocation.
// NOTE: default round-robin bid->XCD mapping partitions A-panels across XCDs
// (x = bid mod 64; XCD k gets x === k mod 8 -> 1.57 MB A working set per XCD,
// L2-resident, reused 12x). A contiguous-chunk XCD swizzle would give each XCD
// the whole 12.6 MB A -- analytically worse; do not swizzle this grid.
__global__ __launch_bounds__(256) void proj_kernel(
    const unsigned short* __restrict__ xq_ln, const unsigned short* __restrict__ xkv_ln,
    const unsigned short* __restrict__ WqT, const unsigned short* __restrict__ WkvT,
    unsigned short* __restrict__ Qb, unsigned short* __restrict__ Kb,
    unsigned short* __restrict__ Vt,
    const float* __restrict__ freqs_q, const float* __restrict__ freqs_k)
{
    int bid = blockIdx.x;
    const unsigned short* A; const unsigned short* Bt; int mode, bm, bn;
    const float* fr; unsigned short* oQ; unsigned short* oK; unsigned short* oV;
    if (bid < 768) {
        int x = bid & 63, y = bid >> 6;       // 64 x 12
        A = xkv_ln; Bt = WkvT; mode = 1; bm = x * 128; bn = y * 128;
        fr = freqs_k; oQ = nullptr; oK = Kb; oV = Vt;
    } else {
        int b2 = bid - 768;
        int x = b2 & 63, y = b2 >> 6;         // 64 x 6
        A = xq_ln; Bt = WqT; mode = 0; bm = x * 128; bn = y * 128;
        fr = freqs_q; oQ = Qb; oK = nullptr; oV = nullptr;
    }
    gemm_body<128>(A, Bt, E_, mode, bm, bn, oQ, fr, oK, oV, nullptr, nullptr, nullptr);
}

// ---------------- flash attention: 32x32 MFMA, register P-transform, 2-buf gll -----
// grid: (x = bh  [XCD-stationary K/V], y = q-block)
// Round-14: r12 compute body (verified best) with LDS cut 48KB -> 32KB
// (2 buffers, depth-1 prefetch, vmcnt(0) per tile). Motivation: measured
// OccupancyPercent has been pinned at 24-25% = 8 waves/CU = 2 blocks/CU for
// ten rounds, though 48KB should allow 3 blocks -- consistent with effective
// LDS allocation granularity rounding 48KB up to 64KB. At 32KB, 3+ blocks
// fit even at coarse granularity -> predicted occupancy 24->35-37%, attn
// 79 -> 68-73 us. Depth-1 vs depth-2 precedent: r1 (2-buf) 87.3 ~= r3
// (3-buf) 86.9 -- pipeline depth is free; K/V is L2-resident (~200-400cy)
// vs ~1500cy compute phase, so the vmcnt(0) drain costs ~nothing.
// r13's s_sleep stagger: removed (null result, within noise).
// CORRECTNESS NOTE (r11): the s_setprio brackets are LOAD-BEARING spacers
// around the permlane->MFMA sequence -- do not remove without re-verifying.
// VGPR law (r7/r8/r10): <=84 VGPR keeps occupancy; >=96 drops it.
__global__ __launch_bounds__(256, 4) void attn_kernel(
    const unsigned short* __restrict__ Qg, const unsigned short* __restrict__ Kg,
    const unsigned short* __restrict__ Vt, unsigned short* __restrict__ O)
{
    // [0..8191] K bufs (2 x 4096 shorts), [8192..16383] V bufs  (32 KB total)
    __shared__ __align__(16) unsigned short smem[2 * 4096 * 2];

    int tid = threadIdx.x;
    int wave = tid >> 6, lane = tid & 63;
    int l32 = lane & 31, hi = lane >> 5;
    int bh = blockIdx.x;
    int b = bh / H_, h = bh % H_;
    int qbase = blockIdx.y * 128 + wave * 32;

    const size_t head = (size_t)bh * LK_ * D_;
    const unsigned short* Qh = Qg + head;
    const unsigned short* Kh = Kg + head;
    const unsigned short* Vh = Vt + head;   // [d][key]

    // Q fragments: B-operand [k=d][n=q]: lane(n=l32,hi): d = dc*16 + hi*8 + j
    short8 qf[4];
#pragma unroll
    for (int dc = 0; dc < 4; dc++)
        qf[dc] = *(const short8*)(Qh + (size_t)(qbase + l32) * D_ + dc * 16 + hi * 8);

    f32x16 oacc[2] = {};
    float lsum = 0.f;

    int ro = lane >> 3, cx = lane & 7;
    int sco = ((cx ^ ro) * 8);
    int sw = l32 & 7;
    int hs = hi ^ sw;

    // 4 per-lane LDS element-offset bases; all 16 per-tile ds_reads are
    // bs[c] + compile-time offset. (c = dc for QK, c = half*2+kk for PV.)
    // Identity: ((c*2+hi)^sw)*8 == ((c*2)^(hi^sw))*8  (c*2 even, hi bit0).
    unsigned bs[4];
#pragma unroll
    for (int c = 0; c < 4; c++)
        bs[c] = l32 * 64 + (((c * 2) ^ hs) * 8);

    // staging base pointers (tile 0), advanced by constants per stage
    const unsigned short* kst = Kh + (size_t)(wave * 16 + ro) * D_ + sco;
    const unsigned short* vst = Vh + (size_t)(wave * 16 + ro) * LK_ + sco;

    // stage tile (ptrs pre-offset) into LDS buffer bf
    auto stage = [&](const unsigned short* Kp, const unsigned short* Vp, int bf) {
        gll16(Kp,            &smem[bf * 4096 + (wave * 16) * 64]);
        gll16(Kp + 8 * D_,   &smem[bf * 4096 + (wave * 16 + 8) * 64]);
        gll16(Vp,            &smem[8192 + bf * 4096 + (wave * 16) * 64]);
        gll16(Vp + 8 * LK_,  &smem[8192 + bf * 4096 + (wave * 16 + 8) * 64]);
    };

    // compute one 64-key tile from buffer BF (compile-time)
    auto compute = [&](auto bfc) {
        constexpr int bf = decltype(bfc)::v;
        constexpr int KO = bf * 4096;            // K buf base (shorts)
        constexpr int VO = 8192 + bf * 4096;     // V buf base (shorts)

        // Both halves' S^T chains, interleaved (independent MFMA chains).
        f32x16 st0 = {}, st1 = {};
        __builtin_amdgcn_s_setprio(1);
#pragma unroll
        for (int dc = 0; dc < 4; dc++) {
            short8 k0 = *(const short8*)&smem[bs[dc] + KO];
            short8 k1 = *(const short8*)&smem[bs[dc] + KO + 2048];
            st0 = __builtin_amdgcn_mfma_f32_32x32x16_bf16(k0, qf[dc], st0, 0, 0, 0);
            st1 = __builtin_amdgcn_mfma_f32_32x32x16_bf16(k1, qf[dc], st1, 0, 0, 0);
        }
        __builtin_amdgcn_s_setprio(0);

        // softmax batch: exp2 + lsum (VALU) + packed bf16 convert, both halves
        unsigned pks0[8], pks1[8];
#pragma unroll
        for (int t = 0; t < 8; t++) {
            float p0 = __builtin_amdgcn_exp2f(st0[2 * t]);
            float p1 = __builtin_amdgcn_exp2f(st0[2 * t + 1]);
            lsum += p0 + p1;
            pks0[t] = pkcvt(p0, p1);
        }
#pragma unroll
        for (int t = 0; t < 8; t++) {
            float p0 = __builtin_amdgcn_exp2f(st1[2 * t]);
            float p1 = __builtin_amdgcn_exp2f(st1[2 * t + 1]);
            lsum += p0 + p1;
            pks1[t] = pkcvt(p0, p1);
        }
        // cross-half key exchange, in-register: after the swaps,
        // pks[kk*4 .. kk*4+3] are exactly the PV A-fragment words g0..g3.
        asm("v_permlane32_swap_b32 %0, %1" : "+v"(pks0[0]), "+v"(pks0[2]));
        asm("v_permlane32_swap_b32 %0, %1" : "+v"(pks0[1]), "+v"(pks0[3]));
        asm("v_permlane32_swap_b32 %0, %1" : "+v"(pks0[4]), "+v"(pks0[6]));
        asm("v_permlane32_swap_b32 %0, %1" : "+v"(pks0[5]), "+v"(pks0[7]));
        asm("v_permlane32_swap_b32 %0, %1" : "+v"(pks1[0]), "+v"(pks1[2]));
        asm("v_permlane32_swap_b32 %0, %1" : "+v"(pks1[1]), "+v"(pks1[3]));
        asm("v_permlane32_swap_b32 %0, %1" : "+v"(pks1[4]), "+v"(pks1[6]));
        asm("v_permlane32_swap_b32 %0, %1" : "+v"(pks1[5]), "+v"(pks1[7]));

        // PV: A = P[q][key] assembled in-register, B = Vt[d][key].
        __builtin_amdgcn_s_setprio(1);
#pragma unroll
        for (int half = 0; half < 2; half++) {
#pragma unroll
            for (int kk = 0; kk < 2; kk++) {
                union { unsigned u[4]; short8 s8; } pf;
#pragma unroll
                for (int g = 0; g < 4; g++)
                    pf.u[g] = half ? pks1[kk * 4 + g] : pks0[kk * 4 + g];
#pragma unroll
                for (int dt = 0; dt < 2; dt++) {
                    short8 vfr = *(const short8*)&smem[bs[half * 2 + kk] + VO + dt * 2048];
                    oacc[dt] = __builtin_amdgcn_mfma_f32_32x32x16_bf16(pf.s8, vfr, oacc[dt], 0, 0, 0);
                }
            }
        }
        __builtin_amdgcn_s_setprio(0);
    };

    // prologue: stage tile 0 into buf 0
    stage(kst, vst, 0);
    asm volatile("s_waitcnt vmcnt(0)\ns_barrier" ::: "memory");

    // main loop: tiles 0..29, unrolled x2 so buf index is compile-time;
    // depth-1 prefetch, one barrier per tile with vmcnt(0) (4 outstanding
    // loads for tile t+1 drained after tile t's compute -- ~200-400cy L2
    // latency fully covered by the ~1500cy compute phase).
    for (int it = 0; it < 15; ++it) {
        int t = 2 * it;
        stage(kst + (size_t)(t + 1) * 4096, vst + (size_t)(t + 1) * 64, 1);
        compute(IC<0>{});
        asm volatile("s_waitcnt vmcnt(0) lgkmcnt(0)\ns_barrier" ::: "memory");
        stage(kst + (size_t)(t + 2) * 4096, vst + (size_t)(t + 2) * 64, 0);
        compute(IC<1>{});
        asm volatile("s_waitcnt vmcnt(0) lgkmcnt(0)\ns_barrier" ::: "memory");
    }
    // t=30 in buf 0: stage tile 31, compute 30
    stage(kst + (size_t)31 * 4096, vst + (size_t)31 * 64, 1);
    compute(IC<0>{});
    asm volatile("s_waitcnt vmcnt(0) lgkmcnt(0)\ns_barrier" ::: "memory");
    // tile 31 (buf 1)
    compute(IC<1>{});

    // epilogue: total row sums, normalize, store
    lsum += __shfl_xor(lsum, 32);
    float inv = 1.f / lsum;
#pragma unroll
    for (int reg = 0; reg < 16; reg++) {
        int ql = (reg & 3) + 8 * (reg >> 2) + 4 * hi;
        float iq = __shfl(inv, ql);
        int q = qbase + ql;
        size_t base = ((size_t)b * LQ_ + q) * E_ + h * D_;
#pragma unroll
        for (int dt = 0; dt < 2; dt++)
            O[base + dt * 32 + l32] = f2bf(oacc[dt][reg] * iq);
    }
}

extern "C" void kernel_launch(void* const* d_in, const int* in_sizes, int n_in,
                              void* d_out, int out_size, void* d_ws, size_t ws_size,
                              hipStream_t stream)
{
    const float* x_q     = (const float*)d_in[0];
    const float* x_kv    = (const float*)d_in[1];
    const float* freqs_q = (const float*)d_in[2];
    const float* freqs_k = (const float*)d_in[3];
    const float* Wq      = (const float*)d_in[4];
    const float* Wkv     = (const float*)d_in[5];
    const float* Wo      = (const float*)d_in[6];
    const float* bo      = (const float*)d_in[7];
    const float* ln_q_g  = (const float*)d_in[8];
    const float* ln_q_b  = (const float*)d_in[9];
    const float* ln_kv_g = (const float*)d_in[10];
    const float* ln_kv_b = (const float*)d_in[11];
    const float* gain    = (const float*)d_in[12];
    float* out = (float*)d_out;

    unsigned short* ws = (unsigned short*)d_ws;
    const size_t SZ = (size_t)B_ * LQ_ * E_;  // 6291456
    unsigned short* xq_ln  = ws;
    unsigned short* xkv_ln = xq_ln + SZ;
    unsigned short* Qb     = xkv_ln + SZ;
    unsigned short* Kb     = Qb + SZ;
    unsigned short* Vt     = Kb + SZ;          // filled transposed by KV-GEMM
    unsigned short* Ob     = xq_ln;            // reuse (dead after Q GEMM)
    unsigned short* WqT    = Vt + SZ;
    unsigned short* WkvT   = WqT + E_ * E_;
    unsigned short* WoT    = WkvT + 2 * E_ * E_;

    ln_tr_kernel<<<7552, 256, 0, stream>>>(x_q, x_kv, ln_q_g, ln_q_b, ln_kv_g, ln_kv_b,
                                           xq_ln, xkv_ln, Wq, Wkv, Wo, WqT, WkvT, WoT);
    proj_kernel<<<1152, 256, 0, stream>>>(xq_ln, xkv_ln, WqT, WkvT, Qb, Kb, Vt,
                                          freqs_q, freqs_k);
    attn_kernel<<<dim3(48, 16), 256, 0, stream>>>(Qb, Kb, Vt, Ob);
    // O-proj at BMT=64: grid (128,6) = 768 blocks = exactly 3.0 blocks/CU.
    // (r9: BMT=128's 384 blocks = 1.5/CU load imbalance cost +35 us -- tile
    // efficiency is subordinate to grid/CU balance at small grids.)
    gemm_kernel<64><<<dim3(128, 6), 256, 0, stream>>>(Ob, WoT, E_, 2,
                                                      nullptr, nullptr, nullptr, nullptr, out, bo, gain);
}